// Round 13
// baseline (588.744 us; speedup 1.0000x reference)
//
#include <hip/hip_runtime.h>

#define HID    128
#define GATES  512      // 4*HID
#define EMB    64
#define TSTEPS 1024
#define BATCH  512
#define VOCAB  50257
#define NCLS   28
#define H8STRIDE 160    // h row stride in BYTES (i8 h)
#define TPAD   8        // token row pad (ints)
#define TTAIL  4        // token tail pad: prefetch never needs a clamp

// gate pre-scale folded into proj and w_hh scales: i,f,o -> -log2e; g -> -2log2e
#define S_SIG  (-1.442695041f)
#define S_TANH (-2.885390082f)

typedef __attribute__((ext_vector_type(8))) short short8;   // 8 bf16 = 4 VGPRs
typedef __attribute__((ext_vector_type(4))) float f32x4;
typedef __attribute__((ext_vector_type(4))) unsigned short us4;
typedef __attribute__((ext_vector_type(4))) int int4v;

// lgkm-only barrier: LDS visibility without draining global (vmcnt) loads.
#define BAR_LGKM() __asm__ __volatile__("s_waitcnt lgkmcnt(0)\n\ts_barrier" ::: "memory")

static __device__ __forceinline__ float bf2f(unsigned short u){
  union { unsigned int i; float f; } v; v.i = ((unsigned int)u) << 16; return v.f;
}
static __device__ __forceinline__ unsigned short f2bf(float f){
  union { float ff; unsigned int i; } v; v.ff = f;
  unsigned int x = v.i;
  x += 0x7fffu + ((x >> 16) & 1u);   // round-to-nearest-even
  return (unsigned short)(x >> 16);
}

// ---------------------------------------------------------------------------
// Phase 1: proj[v][hcol][type] = s_type * (emb[v]·w_ih[g] + b_ih[g] + b_hh[g]),
// g = type*128 + hcol, stored bf16 interleaved. R11 version (measured 61 µs):
// inline split-bf16 (hi+lo) MFMA -> f32-accurate; LDS stage, coalesced store.
// ---------------------------------------------------------------------------
__global__ __launch_bounds__(256) void emb_proj_kernel(
    const float* __restrict__ emb,     // [V][64]
    const float* __restrict__ w_ih,    // [512][64]
    const float* __restrict__ b_ih,    // [512]
    const float* __restrict__ b_hh,    // [512]
    unsigned short* __restrict__ proj) // [V][512] interleaved bf16
{
  __shared__ float stage[16][516];     // [vrow][hcol*4+type], padded row

  int wave = threadIdx.x >> 6;         // 0..3 == gate type t
  int lane = threadIdx.x & 63;
  int n = lane & 15;
  int q = lane >> 4;
  long v0 = (long)blockIdx.x * 16;
  const float scl = (wave == 2) ? S_TANH : S_SIG;

  long vrow = v0 + n; if (vrow >= VOCAB) vrow = VOCAB - 1;
  const float* er = emb + vrow * EMB;
  short8 ahi[2], alo[2];
  #pragma unroll
  for (int ch = 0; ch < 2; ++ch){
    #pragma unroll
    for (int j = 0; j < 8; ++j){
      float xv = er[ch * 32 + q * 8 + j];
      unsigned short h = f2bf(xv);
      ahi[ch][j] = (short)h;
      alo[ch][j] = (short)f2bf(xv - bf2f(h));
    }
  }

  #pragma unroll
  for (int i = 0; i < 8; ++i){
    int g0 = (wave * 8 + i) * 16;               // gate base; type = wave
    const float* wr = w_ih + (long)(g0 + n) * EMB;
    short8 bhi[2], blo[2];
    #pragma unroll
    for (int ch = 0; ch < 2; ++ch){
      #pragma unroll
      for (int j = 0; j < 8; ++j){
        float xv = wr[ch * 32 + q * 8 + j];
        unsigned short h = f2bf(xv);
        bhi[ch][j] = (short)h;
        blo[ch][j] = (short)f2bf(xv - bf2f(h));
      }
    }
    float bias = b_ih[g0 + n] + b_hh[g0 + n];
    f32x4 acc = {bias, bias, bias, bias};
    #pragma unroll
    for (int ch = 0; ch < 2; ++ch){
      acc = __builtin_amdgcn_mfma_f32_16x16x32_bf16(ahi[ch], bhi[ch], acc, 0, 0, 0);
      acc = __builtin_amdgcn_mfma_f32_16x16x32_bf16(ahi[ch], blo[ch], acc, 0, 0, 0);
      acc = __builtin_amdgcn_mfma_f32_16x16x32_bf16(alo[ch], bhi[ch], acc, 0, 0, 0);
    }
    #pragma unroll
    for (int r = 0; r < 4; ++r)
      stage[q * 4 + r][(i * 16 + n) * 4 + wave] = scl * acc[r];
  }
  __syncthreads();

  {
    int row = threadIdx.x >> 4;          // 0..15
    int c0  = (threadIdx.x & 15) * 32;   // 0..480
    long grow = v0 + row;
    if (grow < VOCAB){
      unsigned short* dst = proj + grow * GATES + c0;
      #pragma unroll
      for (int k = 0; k < 8; ++k){
        us4 v;
        #pragma unroll
        for (int m = 0; m < 4; ++m) v[m] = f2bf(stage[row][c0 + k * 4 + m]);
        *(us4*)(dst + k * 4) = v;
      }
    }
  }
}

// ---------------------------------------------------------------------------
// Phase 2: LSTM recurrence + final linear, i8 MFMA + asymmetric wave roles.
// 256 blocks x 512 threads, R=2 rows/block, 2 waves/SIMD (waves w and w+4).
// Both waves do their 8 i8 MFMAs (16/SIMD, the structural optimum). Then:
//   wave w+4: writes its 32 cells' raw i32 gates (q<2 lanes, b128) -> LDS.
//   BAR1. wave w alone: 64 cells (own 32 in regs, partner 32 via one b128
//   read), ONE cell per lane -> per-SIMD nonlin/gather issue HALVED.
//   BAR2 (h visible). Waves 4-7 idle between BAR1/BAR2 -> their SIMD's
//   issue slots are free for wave w's nonlinearity.
// Per-hcol dequant scales in a small LDS table (built once at init).
// ---------------------------------------------------------------------------
__global__ __launch_bounds__(512, 2) void lstm_kernel(
    const int* __restrict__ x,           // [512][1024] int32
    const float* __restrict__ w_hh,      // [512][128] f32
    const unsigned short* __restrict__ proj, // [V][512] bf16 interleaved
    const float* __restrict__ w_lin,     // [28][128] f32
    const float* __restrict__ b_lin,     // [28] f32
    float* __restrict__ out)             // [512][28] f32
{
  __shared__ int   tok_lds[2][TSTEPS + TPAD];   // tok*GATES, bank-padded
  __shared__ signed char h8[2][2][H8STRIDE];    // [buf][row][hcol] i8 h
  __shared__ float scl_lds[HID][4];             // per-hcol dequant scales
  __shared__ int   gate_xch[8][16][4];          // [slot][n][t] raw i32 gates

  int tid  = threadIdx.x;
  int wave = tid >> 6;          // 0..7; (w, w+4) share a SIMD
  int lane = tid & 63;
  int n = lane & 15;
  int q = lane >> 4;
  int r0 = blockIdx.x * 2;

  // --- preload tokens (pre-multiplied element offsets) ------------------
  for (int i = tid; i < TSTEPS + TTAIL; i += 512){
    int src = i < TSTEPS ? i : TSTEPS - 1;
    tok_lds[0][i] = x[(long)r0 * TSTEPS + src] * GATES;
    tok_lds[1][i] = x[(long)(r0 + 1) * TSTEPS + src] * GATES;
  }

  // --- quantize w_hh to i8, per-gate-row max scale ----------------------
  int4v Bw[4][2];
  float sclw[4];
  #pragma unroll
  for (int t = 0; t < 4; ++t){
    int row = t * 128 + wave * 16 + n;
    const float* wr = w_hh + (long)row * HID;
    float vals[2][16];
    float m = 0.f;
    #pragma unroll
    for (int ch = 0; ch < 2; ++ch)
      #pragma unroll
      for (int j = 0; j < 16; ++j){
        float v = wr[ch * 64 + q * 16 + j];
        vals[ch][j] = v;
        m = fmaxf(m, fabsf(v));
      }
    m = fmaxf(m, __shfl_xor(m, 16, 64));
    m = fmaxf(m, __shfl_xor(m, 32, 64));
    m = fmaxf(m, 1e-20f);
    float qs = 127.f / m;
    #pragma unroll
    for (int ch = 0; ch < 2; ++ch){
      #pragma unroll
      for (int d = 0; d < 4; ++d){
        int b0 = (int)__builtin_rintf(vals[ch][d * 4 + 0] * qs);
        int b1 = (int)__builtin_rintf(vals[ch][d * 4 + 1] * qs);
        int b2 = (int)__builtin_rintf(vals[ch][d * 4 + 2] * qs);
        int b3 = (int)__builtin_rintf(vals[ch][d * 4 + 3] * qs);
        Bw[t][ch][d] = (b0 & 255) | ((b1 & 255) << 8) | ((b2 & 255) << 16) | (b3 << 24);
      }
    }
    sclw[t] = ((t == 2) ? S_TANH : S_SIG) * m * (1.f / 16129.f);  // /127^2
  }
  if (q == 0)
    *(f32x4*)&scl_lds[wave * 16 + n][0] = (f32x4){sclw[0], sclw[1], sclw[2], sclw[3]};

  // zero h buffers (h0 = 0)
  for (int i = tid; i < 2 * 2 * H8STRIDE; i += 512) ((signed char*)h8)[i] = 0;

  __syncthreads();                       // tokens + h zeros + scl table

  // --- per-lane cell assignment (nonlin waves 0-3 only) -----------------
  bool isnl = (wave < 4);
  int  crow  = q & 1;                              // cell batch row
  int  chcol = (((q < 2 ? wave : wave + 4) & 7) << 4) + n;  // cell hcol
  f32x4 scl4 = *(const f32x4*)&scl_lds[chcol][0];
  int  ghcol4 = chcol * 4;
  int  arow = (n >> 2) & 1;                        // h row for A-frag
  int  xslot = wave * 2 + crow;                    // partner gate slot

  float c_state = 0.f;
  int4v acc[4] = {};

  // --- depth-2 gx prefetch (nonlin waves only) --------------------------
  us4 hxA = {}, hxB = {};
  if (isnl){
    hxA = *(const us4*)(proj + (long)(tok_lds[crow][0] + ghcol4));
    hxB = *(const us4*)(proj + (long)(tok_lds[crow][1] + ghcol4));
  }

#define SUBSTEP(RB, HX, NSTEP)                                                \
  {                                                                           \
    int4v Af[2];                                                              \
    _Pragma("unroll")                                                         \
    for (int ch = 0; ch < 2; ++ch)                                            \
      Af[ch] = *(const int4v*)(&h8[RB][arow][ch * 64 + q * 16]);              \
    _Pragma("unroll")                                                         \
    for (int t = 0; t < 4; ++t) acc[t][0] = 0;                                \
    _Pragma("unroll")                                                         \
    for (int ch = 0; ch < 2; ++ch)                                            \
      _Pragma("unroll")                                                       \
      for (int t = 0; t < 4; ++t)                                             \
        acc[t] = __builtin_amdgcn_mfma_i32_16x16x64_i8(                       \
            Af[ch], Bw[t][ch], acc[t], 0, 0, 0);                              \
    if (wave >= 4){                                                           \
      if (q < 2)                                                              \
        *(int4v*)(&gate_xch[(wave - 4) * 2 + q][n][0]) =                      \
            (int4v){acc[0][0], acc[1][0], acc[2][0], acc[3][0]};              \
    }                                                                         \
    BAR_LGKM();                        /* gates visible */                    \
    if (isnl){                                                                \
      int4v rL = *(const int4v*)(&gate_xch[xslot][n][0]);                     \
      float g0 = (float)(q < 2 ? acc[0][0] : rL[0]) * scl4[0] + bf2f(HX[0]);  \
      float g1 = (float)(q < 2 ? acc[1][0] : rL[1]) * scl4[1] + bf2f(HX[1]);  \
      float g2 = (float)(q < 2 ? acc[2][0] : rL[2]) * scl4[2] + bf2f(HX[2]);  \
      float g3 = (float)(q < 2 ? acc[3][0] : rL[3]) * scl4[3] + bf2f(HX[3]);  \
      HX = *(const us4*)(proj + (long)(tok_lds[crow][NSTEP] + ghcol4));       \
      float ei = __builtin_amdgcn_exp2f(g0);                                  \
      float ef = __builtin_amdgcn_exp2f(g1);                                  \
      float eg = __builtin_amdgcn_exp2f(fminf(g2, 126.f));                    \
      float eo = __builtin_amdgcn_exp2f(g3);                                  \
      float r1 = __builtin_amdgcn_rcpf((1.f + ei) * (1.f + eg));              \
      float sitg = (1.f - eg) * r1;           /* si * tg */                   \
      float sf = __builtin_amdgcn_rcpf(1.f + ef);                             \
      c_state = sf * c_state + sitg;                                          \
      float ec = __builtin_amdgcn_exp2f(fminf(S_TANH * c_state, 126.f));      \
      float r2 = __builtin_amdgcn_rcpf((1.f + eo) * (1.f + ec));              \
      float hv = (1.f - ec) * r2;             /* tanh(c) * so */              \
      h8[(RB) ^ 1][crow][chcol] = (signed char)(int)__builtin_rintf(hv * 127.f); \
    }                                                                         \
    BAR_LGKM();                        /* h visible */                        \
  }

  for (int step = 0; step < TSTEPS; step += 2){
    SUBSTEP(0, hxA, step + 2)
    SUBSTEP(1, hxB, step + 3)
  }
#undef SUBSTEP

  // --- final linear: out[r0+b][j] = (qh[b]/127) . w_lin[j] + b_lin[j] ---
  // TSTEPS even -> final h is in h8[0]
  if (tid < 2 * NCLS){
    int b = tid / NCLS, j = tid - b * NCLS;
    float s = 0.f;
    const float* wl = w_lin + (long)j * HID;
    #pragma unroll 4
    for (int k = 0; k < HID; ++k)
      s += (float)h8[0][b][k] * wl[k];
    out[(long)(r0 + b) * NCLS + j] = b_lin[j] + s * (1.f / 127.f);
  }
}

// ---------------------------------------------------------------------------
extern "C" void kernel_launch(void* const* d_in, const int* in_sizes, int n_in,
                              void* d_out, int out_size, void* d_ws, size_t ws_size,
                              hipStream_t stream)
{
  const int*   x     = (const int*)d_in[0];
  const float* emb   = (const float*)d_in[1];
  const float* w_ih  = (const float*)d_in[2];
  const float* w_hh  = (const float*)d_in[3];
  const float* b_ih  = (const float*)d_in[4];
  const float* b_hh  = (const float*)d_in[5];
  const float* w_lin = (const float*)d_in[6];
  const float* b_lin = (const float*)d_in[7];
  float*       out   = (float*)d_out;
  unsigned short* proj = (unsigned short*)d_ws;   // [V][512] bf16, ~51.5 MB

  int vblocks = (VOCAB + 15) / 16;   // 3142
  emb_proj_kernel<<<dim3(vblocks), dim3(256), 0, stream>>>(
      emb, w_ih, b_ih, b_hh, proj);
  lstm_kernel<<<dim3(BATCH / 2), dim3(512), 0, stream>>>(
      x, w_hh, proj, w_lin, b_lin, out);
}

// Round 14
// 521.852 us; speedup vs baseline: 1.1282x; 1.1282x over previous
//
#include <hip/hip_runtime.h>

#define HID    128
#define GATES  512      // 4*HID
#define EMB    64
#define TSTEPS 1024
#define BATCH  512
#define VOCAB  50257
#define NCLS   28
#define H8STRIDE 160    // h row stride in BYTES (i8 h)
#define TPAD   8        // token row pad (ints)
#define TTAIL  4        // token tail pad: prefetch never needs a clamp

// gate pre-scale folded into proj and w_hh scales: i,f,o -> -log2e; g -> -2log2e
#define S_SIG  (-1.442695041f)
#define S_TANH (-2.885390082f)

typedef __attribute__((ext_vector_type(8))) short short8;   // 8 bf16 = 4 VGPRs
typedef __attribute__((ext_vector_type(4))) float f32x4;
typedef __attribute__((ext_vector_type(4))) unsigned short us4;
typedef __attribute__((ext_vector_type(4))) int int4v;

// lgkm-only barrier: LDS visibility without draining global (vmcnt) loads.
#define BAR_LGKM() __asm__ __volatile__("s_waitcnt lgkmcnt(0)\n\ts_barrier" ::: "memory")

static __device__ __forceinline__ float bf2f(unsigned short u){
  union { unsigned int i; float f; } v; v.i = ((unsigned int)u) << 16; return v.f;
}
static __device__ __forceinline__ unsigned short f2bf(float f){
  union { float ff; unsigned int i; } v; v.ff = f;
  unsigned int x = v.i;
  x += 0x7fffu + ((x >> 16) & 1u);   // round-to-nearest-even
  return (unsigned short)(x >> 16);
}

// ---------------------------------------------------------------------------
// Phase 1: proj[v][hcol][type] = s_type * (emb[v]·w_ih[g] + b_ih[g] + b_hh[g]),
// g = type*128 + hcol, stored bf16 interleaved. Verified (R11/R13).
// ---------------------------------------------------------------------------
__global__ __launch_bounds__(256) void emb_proj_kernel(
    const float* __restrict__ emb,     // [V][64]
    const float* __restrict__ w_ih,    // [512][64]
    const float* __restrict__ b_ih,    // [512]
    const float* __restrict__ b_hh,    // [512]
    unsigned short* __restrict__ proj) // [V][512] interleaved bf16
{
  __shared__ float stage[16][516];     // [vrow][hcol*4+type], padded row

  int wave = threadIdx.x >> 6;         // 0..3 == gate type t
  int lane = threadIdx.x & 63;
  int n = lane & 15;
  int q = lane >> 4;
  long v0 = (long)blockIdx.x * 16;
  const float scl = (wave == 2) ? S_TANH : S_SIG;

  long vrow = v0 + n; if (vrow >= VOCAB) vrow = VOCAB - 1;
  const float* er = emb + vrow * EMB;
  short8 ahi[2], alo[2];
  #pragma unroll
  for (int ch = 0; ch < 2; ++ch){
    #pragma unroll
    for (int j = 0; j < 8; ++j){
      float xv = er[ch * 32 + q * 8 + j];
      unsigned short h = f2bf(xv);
      ahi[ch][j] = (short)h;
      alo[ch][j] = (short)f2bf(xv - bf2f(h));
    }
  }

  #pragma unroll
  for (int i = 0; i < 8; ++i){
    int g0 = (wave * 8 + i) * 16;               // gate base; type = wave
    const float* wr = w_ih + (long)(g0 + n) * EMB;
    short8 bhi[2], blo[2];
    #pragma unroll
    for (int ch = 0; ch < 2; ++ch){
      #pragma unroll
      for (int j = 0; j < 8; ++j){
        float xv = wr[ch * 32 + q * 8 + j];
        unsigned short h = f2bf(xv);
        bhi[ch][j] = (short)h;
        blo[ch][j] = (short)f2bf(xv - bf2f(h));
      }
    }
    float bias = b_ih[g0 + n] + b_hh[g0 + n];
    f32x4 acc = {bias, bias, bias, bias};
    #pragma unroll
    for (int ch = 0; ch < 2; ++ch){
      acc = __builtin_amdgcn_mfma_f32_16x16x32_bf16(ahi[ch], bhi[ch], acc, 0, 0, 0);
      acc = __builtin_amdgcn_mfma_f32_16x16x32_bf16(ahi[ch], blo[ch], acc, 0, 0, 0);
      acc = __builtin_amdgcn_mfma_f32_16x16x32_bf16(alo[ch], bhi[ch], acc, 0, 0, 0);
    }
    #pragma unroll
    for (int r = 0; r < 4; ++r)
      stage[q * 4 + r][(i * 16 + n) * 4 + wave] = scl * acc[r];
  }
  __syncthreads();

  {
    int row = threadIdx.x >> 4;          // 0..15
    int c0  = (threadIdx.x & 15) * 32;   // 0..480
    long grow = v0 + row;
    if (grow < VOCAB){
      unsigned short* dst = proj + grow * GATES + c0;
      #pragma unroll
      for (int k = 0; k < 8; ++k){
        us4 v;
        #pragma unroll
        for (int m = 0; m < 4; ++m) v[m] = f2bf(stage[row][c0 + k * 4 + m]);
        *(us4*)(dst + k * 4) = v;
      }
    }
  }
}

// ---------------------------------------------------------------------------
// Phase 2: LSTM recurrence + final linear. R12 structure (best measured:
// 443 µs) + t-major MFMA with EARLY per-tile dequant: tile t's gate is
// converted and its exp2 fired while tiles t+1..3 still occupy the matrix
// pipe -> trans-chain head overlaps MFMA tail. f-gate scheduled first
// (c_state needs sf earliest). Everything else identical to R12:
// 256 blocks x 512 threads, R=2, 2 waves/SIMD, i8 16x16x64 MFMA (8/wave),
// per-gate-row max-scaled w_hh, all-lane nonlin via C-row duplicates,
// one lgkm-only barrier per step, depth-2 dwordx2 gx prefetch.
// ---------------------------------------------------------------------------
__global__ __launch_bounds__(512, 2) void lstm_kernel(
    const int* __restrict__ x,           // [512][1024] int32
    const float* __restrict__ w_hh,      // [512][128] f32
    const unsigned short* __restrict__ proj, // [V][512] bf16 interleaved
    const float* __restrict__ w_lin,     // [28][128] f32
    const float* __restrict__ b_lin,     // [28] f32
    float* __restrict__ out)             // [512][28] f32
{
  __shared__ int   tok_lds[2][TSTEPS + TPAD];   // tok*GATES, bank-padded
  __shared__ signed char h8[2][2][H8STRIDE];    // [buf][row][hcol] i8 h

  int tid  = threadIdx.x;
  int wave = tid >> 6;          // 0..7
  int lane = tid & 63;
  int n = lane & 15;
  int q = lane >> 4;
  int r0 = blockIdx.x * 2;

  // --- preload tokens (pre-multiplied element offsets) ------------------
  for (int i = tid; i < TSTEPS + TTAIL; i += 512){
    int src = i < TSTEPS ? i : TSTEPS - 1;
    tok_lds[0][i] = x[(long)r0 * TSTEPS + src] * GATES;
    tok_lds[1][i] = x[(long)(r0 + 1) * TSTEPS + src] * GATES;
  }

  // --- quantize w_hh to i8, per-gate-row max scale ----------------------
  // tile t: gate row = t*128 + wave*16 + n; B[k = ch*64 + q*16 + j][n]
  int4v Bw[4][2];
  float scl[4];
  #pragma unroll
  for (int t = 0; t < 4; ++t){
    int row = t * 128 + wave * 16 + n;
    const float* wr = w_hh + (long)row * HID;
    float vals[2][16];
    float m = 0.f;
    #pragma unroll
    for (int ch = 0; ch < 2; ++ch)
      #pragma unroll
      for (int j = 0; j < 16; ++j){
        float v = wr[ch * 64 + q * 16 + j];
        vals[ch][j] = v;
        m = fmaxf(m, fabsf(v));
      }
    m = fmaxf(m, __shfl_xor(m, 16, 64));
    m = fmaxf(m, __shfl_xor(m, 32, 64));
    m = fmaxf(m, 1e-20f);
    float qs = 127.f / m;
    #pragma unroll
    for (int ch = 0; ch < 2; ++ch){
      #pragma unroll
      for (int d = 0; d < 4; ++d){
        int b0 = (int)__builtin_rintf(vals[ch][d * 4 + 0] * qs);
        int b1 = (int)__builtin_rintf(vals[ch][d * 4 + 1] * qs);
        int b2 = (int)__builtin_rintf(vals[ch][d * 4 + 2] * qs);
        int b3 = (int)__builtin_rintf(vals[ch][d * 4 + 3] * qs);
        Bw[t][ch][d] = (b0 & 255) | ((b1 & 255) << 8) | ((b2 & 255) << 16) | (b3 << 24);
      }
    }
    scl[t] = ((t == 2) ? S_TANH : S_SIG) * m * (1.f / 16129.f);  // /127^2
  }

  // zero h buffers (h0 = 0)
  for (int i = tid; i < 2 * 2 * H8STRIDE; i += 512) ((signed char*)h8)[i] = 0;

  float c_state = 0.f;                   // q0/q2: row0 cell; q1/q3: row1 (dups)
  bool  nlact = (q < 2);                 // unique owners write h
  int   arow  = (n >> 2) & 1;            // h row this lane supplies to A
  int   grow  = q & 1;                   // gx row this lane gathers
  int   hcol  = wave * 16 + n;

  int4v acc[4] = {};                     // reg0 re-zeroed per step; 1-3 garbage
  int ghcol4 = hcol * 4;                 // element offset within a proj row

  __syncthreads();                       // tokens + h zeros

  // --- depth-2 gx prefetch ----------------------------------------------
  us4 hxA, hxB;
  hxA = *(const us4*)(proj + (long)(tok_lds[grow][0] + ghcol4));
  hxB = *(const us4*)(proj + (long)(tok_lds[grow][1] + ghcol4));

#define SUBSTEP(RB, HX, NSTEP)                                                \
  {                                                                           \
    int4v Af0 = *(const int4v*)(&h8[RB][arow][q * 16]);                       \
    int4v Af1 = *(const int4v*)(&h8[RB][arow][64 + q * 16]);                  \
    us4 hx_cur = HX;                                                          \
    HX = *(const us4*)(proj + (long)(tok_lds[grow][NSTEP] + ghcol4));         \
    /* f-gate tile first: c_state needs sf earliest */                        \
    acc[1][0] = 0;                                                            \
    acc[1] = __builtin_amdgcn_mfma_i32_16x16x64_i8(Af0, Bw[1][0], acc[1], 0, 0, 0); \
    acc[1] = __builtin_amdgcn_mfma_i32_16x16x64_i8(Af1, Bw[1][1], acc[1], 0, 0, 0); \
    float g1 = (float)acc[1][0] * scl[1] + bf2f(hx_cur[1]);                   \
    float ef = __builtin_amdgcn_exp2f(g1);                                    \
    float sf = __builtin_amdgcn_rcpf(1.f + ef);                               \
    acc[0][0] = 0;                                                            \
    acc[0] = __builtin_amdgcn_mfma_i32_16x16x64_i8(Af0, Bw[0][0], acc[0], 0, 0, 0); \
    acc[0] = __builtin_amdgcn_mfma_i32_16x16x64_i8(Af1, Bw[0][1], acc[0], 0, 0, 0); \
    float g0 = (float)acc[0][0] * scl[0] + bf2f(hx_cur[0]);                   \
    float ei = __builtin_amdgcn_exp2f(g0);                                    \
    acc[2][0] = 0;                                                            \
    acc[2] = __builtin_amdgcn_mfma_i32_16x16x64_i8(Af0, Bw[2][0], acc[2], 0, 0, 0); \
    acc[2] = __builtin_amdgcn_mfma_i32_16x16x64_i8(Af1, Bw[2][1], acc[2], 0, 0, 0); \
    float g2 = (float)acc[2][0] * scl[2] + bf2f(hx_cur[2]);                   \
    float eg = __builtin_amdgcn_exp2f(fminf(g2, 126.f));                      \
    acc[3][0] = 0;                                                            \
    acc[3] = __builtin_amdgcn_mfma_i32_16x16x64_i8(Af0, Bw[3][0], acc[3], 0, 0, 0); \
    acc[3] = __builtin_amdgcn_mfma_i32_16x16x64_i8(Af1, Bw[3][1], acc[3], 0, 0, 0); \
    float g3 = (float)acc[3][0] * scl[3] + bf2f(hx_cur[3]);                   \
    float eo = __builtin_amdgcn_exp2f(g3);                                    \
    float r1 = __builtin_amdgcn_rcpf((1.f + ei) * (1.f + eg));                \
    float sitg = (1.f - eg) * r1;             /* si * tg */                   \
    c_state = sf * c_state + sitg;                                            \
    float ec = __builtin_amdgcn_exp2f(fminf(S_TANH * c_state, 126.f));        \
    float r2 = __builtin_amdgcn_rcpf((1.f + eo) * (1.f + ec));                \
    float hv = (1.f - ec) * r2;               /* tanh(c) * so */              \
    if (nlact)                                                                \
      h8[(RB) ^ 1][q][hcol] = (signed char)(int)__builtin_rintf(hv * 127.f);  \
    BAR_LGKM();                                                               \
  }

  for (int step = 0; step < TSTEPS; step += 2){
    SUBSTEP(0, hxA, step + 2)
    SUBSTEP(1, hxB, step + 3)
  }
#undef SUBSTEP

  // --- final linear: out[r0+b][j] = (qh[b]/127) . w_lin[j] + b_lin[j] ---
  // TSTEPS even -> final h is in h8[0]
  if (tid < 2 * NCLS){
    int b = tid / NCLS, j = tid - b * NCLS;
    float s = 0.f;
    const float* wl = w_lin + (long)j * HID;
    #pragma unroll 4
    for (int k = 0; k < HID; ++k)
      s += (float)h8[0][b][k] * wl[k];
    out[(long)(r0 + b) * NCLS + j] = b_lin[j] + s * (1.f / 127.f);
  }
}

// ---------------------------------------------------------------------------
extern "C" void kernel_launch(void* const* d_in, const int* in_sizes, int n_in,
                              void* d_out, int out_size, void* d_ws, size_t ws_size,
                              hipStream_t stream)
{
  const int*   x     = (const int*)d_in[0];
  const float* emb   = (const float*)d_in[1];
  const float* w_ih  = (const float*)d_in[2];
  const float* w_hh  = (const float*)d_in[3];
  const float* b_ih  = (const float*)d_in[4];
  const float* b_hh  = (const float*)d_in[5];
  const float* w_lin = (const float*)d_in[6];
  const float* b_lin = (const float*)d_in[7];
  float*       out   = (float*)d_out;
  unsigned short* proj = (unsigned short*)d_ws;   // [V][512] bf16, ~51.5 MB

  int vblocks = (VOCAB + 15) / 16;   // 3142
  emb_proj_kernel<<<dim3(vblocks), dim3(256), 0, stream>>>(
      emb, w_ih, b_ih, b_hh, proj);
  lstm_kernel<<<dim3(BATCH / 2), dim3(512), 0, stream>>>(
      x, w_hh, proj, w_lin, b_lin, out);
}